// Round 1
// baseline (1738.012 us; speedup 1.0000x reference)
//
#include <hip/hip_runtime.h>
#include <hip/hip_bf16.h>

typedef short bf16x8 __attribute__((ext_vector_type(8)));
typedef float f32x4  __attribute__((ext_vector_type(4)));

#define TM 128
#define TN 128
#define BK 32
#define KD 1024
#define LDP 40   // LDS row pitch in shorts (32 + 8 pad; 80B rows keep 16B alignment)

__device__ __forceinline__ short f2bf(float f) {
  unsigned u = __builtin_bit_cast(unsigned, f);
  u += 0x7fffu + ((u >> 16) & 1u);   // round-to-nearest-even
  return (short)(u >> 16);
}

// Stage a 128x32 fp32 tile -> bf16 LDS tile. Rows >= rowLimit are zero-filled.
__device__ __forceinline__ void load_tile_f32(const float* __restrict__ src, short* dst,
                                              int row0, int k0, int rowLimit, int t) {
#pragma unroll
  for (int p = 0; p < 4; ++p) {
    int idx = t + p * 256;
    int r = idx >> 3, cw = idx & 7;
    int gr = row0 + r;
    float4 v = make_float4(0.f, 0.f, 0.f, 0.f);
    if (gr < rowLimit) v = *(const float4*)(src + (size_t)gr * KD + k0 + cw * 4);
    short4 s;
    s.x = f2bf(v.x); s.y = f2bf(v.y); s.z = f2bf(v.z); s.w = f2bf(v.w);
    *(short4*)&dst[r * LDP + cw * 4] = s;
  }
}

// Stage a 128x32 bf16 tile -> LDS.
__device__ __forceinline__ void load_tile_bf16(const short* __restrict__ src, short* dst,
                                               int row0, int k0, int t) {
#pragma unroll
  for (int p = 0; p < 2; ++p) {
    int idx = t + p * 256;
    int r = idx >> 2, cw = idx & 3;
    bf16x8 v = *(const bf16x8*)(src + (size_t)(row0 + r) * KD + k0 + cw * 8);
    *(bf16x8*)&dst[r * LDP + cw * 8] = v;
  }
}

// C[M,N] = A[M,K] @ B[N,K]^T  (gemm_bt), K = N = 1024 fixed.
// MODE 0: out = C + bias[col]            (fp32 row-major store, rows guarded by M)
// MODE 1: tout[col*1024+row] = bf16(C)   (transposed bf16 store)
// MODE 2: out = C + cvec[z]*kB + bcv     (fp32 row-major store)
template <int MODE, typename BT>
__global__ __launch_bounds__(256) void gemm_bt(
    const float* __restrict__ A, size_t a_bs,
    const BT* __restrict__ B, size_t b_bs,
    float* __restrict__ out, size_t o_bs,
    short* __restrict__ tout, size_t t_bs,
    const float* __restrict__ kB, const float* __restrict__ bcv,
    const float* __restrict__ cvec, int ncv0,
    const float* __restrict__ bias, int M) {
  __shared__ short sA[TM * LDP];
  __shared__ short sB[TN * LDP];
  const int t = threadIdx.x;
  const int z = blockIdx.z;
  const float* Ab = A + (size_t)z * a_bs;
  const BT* Bb = B + (size_t)z * b_bs;
  const int m0 = blockIdx.y * TM, n0 = blockIdx.x * TN;
  const int lane = t & 63, wv = t >> 6;
  const int wm = (wv >> 1) * 64, wn = (wv & 1) * 64;
  const int r16 = lane & 15, q = lane >> 4;

  f32x4 acc[4][4];
  const f32x4 zero4 = {0.f, 0.f, 0.f, 0.f};
#pragma unroll
  for (int i = 0; i < 4; ++i)
#pragma unroll
    for (int j = 0; j < 4; ++j) acc[i][j] = zero4;

  for (int k0 = 0; k0 < KD; k0 += BK) {
    __syncthreads();
    load_tile_f32(Ab, sA, m0, k0, M, t);
    if constexpr (sizeof(BT) == 4)
      load_tile_f32((const float*)Bb, sB, n0, k0, 1 << 30, t);
    else
      load_tile_bf16((const short*)Bb, sB, n0, k0, t);
    __syncthreads();

    bf16x8 af[4], bf[4];
#pragma unroll
    for (int i = 0; i < 4; ++i) {
      af[i] = *(const bf16x8*)&sA[(wm + i * 16 + r16) * LDP + q * 8];
      bf[i] = *(const bf16x8*)&sB[(wn + i * 16 + r16) * LDP + q * 8];
    }
#pragma unroll
    for (int mi = 0; mi < 4; ++mi)
#pragma unroll
      for (int ni = 0; ni < 4; ++ni)
        acc[mi][ni] = __builtin_amdgcn_mfma_f32_16x16x32_bf16(af[mi], bf[ni], acc[mi][ni], 0, 0, 0);
  }

  float cv = 0.f;
  if (MODE == 2) cv = cvec[ncv0 + z];
  float* ob = out ? out + (size_t)z * o_bs : nullptr;

#pragma unroll
  for (int mi = 0; mi < 4; ++mi) {
#pragma unroll
    for (int ni = 0; ni < 4; ++ni) {
      const int row0 = m0 + wm + mi * 16 + q * 4;
      const int col = n0 + wn + ni * 16 + r16;
      f32x4 a = acc[mi][ni];
      if (MODE == 0) {
        float bv = bias[col];
#pragma unroll
        for (int r = 0; r < 4; ++r)
          if (row0 + r < M) ob[(size_t)(row0 + r) * 1024 + col] = a[r] + bv;
      } else if (MODE == 1) {
        short4 s;
        s.x = f2bf(a[0]); s.y = f2bf(a[1]); s.z = f2bf(a[2]); s.w = f2bf(a[3]);
        short* dst = tout + (size_t)z * t_bs + (size_t)col * 1024 + row0;
        *(short4*)dst = s;
      } else {
#pragma unroll
        for (int r = 0; r < 4; ++r) {
          size_t idx = (size_t)(row0 + r) * 1024 + col;
          ob[idx] = a[r] + cv * kB[idx] + bcv[idx];
        }
      }
    }
  }
}

// c[n] = a_mean[n]^T A a_mean[n] + sum_ij a_cov[n,i,j]*A[i,j]
__global__ __launch_bounds__(256) void ckern(const float* __restrict__ a_mean,
                                             const float* __restrict__ a_cov,
                                             const float* __restrict__ kA,
                                             float* __restrict__ c) {
  const int n = blockIdx.x, ch = blockIdx.y, t = threadIdx.x;
  __shared__ float sm[1024];
  for (int j = t; j < 1024; j += 256) sm[j] = a_mean[n * 1024 + j];
  __syncthreads();
  const float4 amv = ((const float4*)sm)[t];
  const size_t cb = ((size_t)n << 20);
  float acc = 0.f;
  for (int i = ch * 64; i < ch * 64 + 64; ++i) {
    float4 Av = ((const float4*)(kA + ((size_t)i << 10)))[t];
    float4 Cv = ((const float4*)(a_cov + cb + ((size_t)i << 10)))[t];
    float pT = Av.x * Cv.x + Av.y * Cv.y + Av.z * Cv.z + Av.w * Cv.w;
    float pS = Av.x * amv.x + Av.y * amv.y + Av.z * amv.z + Av.w * amv.w;
    acc += pT + sm[i] * pS;
  }
#pragma unroll
  for (int off = 32; off > 0; off >>= 1) acc += __shfl_down(acc, off);
  __shared__ float red[4];
  if ((t & 63) == 0) red[t >> 6] = acc;
  __syncthreads();
  if (t == 0) atomicAdd(&c[n], red[0] + red[1] + red[2] + red[3]);
}

extern "C" void kernel_launch(void* const* d_in, const int* in_sizes, int n_in,
                              void* d_out, int out_size, void* d_ws, size_t ws_size,
                              hipStream_t stream) {
  const float* a_mean = (const float*)d_in[0];
  const float* a_cov  = (const float*)d_in[1];
  const float* weight = (const float*)d_in[2];
  const float* bias   = (const float*)d_in[3];
  const float* kA     = (const float*)d_in[4];
  const float* kB     = (const float*)d_in[5];
  const float* b_cov  = (const float*)d_in[6];
  float* h_mean = (float*)d_out;
  float* h_cov  = h_mean + (size_t)64 * 1024;

  float* cvec = (float*)d_ws;
  const size_t TWS_ELEMS = (size_t)64 * 1024 * 1024;   // bf16 elements
  const bool big = ws_size >= 4096 + TWS_ELEMS * 2;
  // T^T[n][l,i] = (a_cov[n] @ W^T)[i,l], bf16.  Fallback: upper half of h_cov region.
  short* Tws = big ? (short*)((char*)d_ws + 4096)
                   : (short*)((char*)h_cov + (size_t)128 * 1024 * 1024);

  hipMemsetAsync(cvec, 0, 64 * sizeof(float), stream);
  ckern<<<dim3(64, 16), 256, 0, stream>>>(a_mean, a_cov, kA, cvec);

  // pass 1: T^T[n] (bf16) from a_cov[n] (A-op) and W (B-op)
  gemm_bt<1, float><<<dim3(8, 8, 64), 256, 0, stream>>>(
      a_cov, (size_t)1 << 20, weight, 0, nullptr, 0, Tws, (size_t)1 << 20,
      nullptr, nullptr, nullptr, 0, nullptr, 1024);

  // h_mean = a_mean @ W^T + bias  (M = 64, guarded)
  gemm_bt<0, float><<<dim3(8, 1, 1), 256, 0, stream>>>(
      a_mean, 0, weight, 0, h_mean, 0, nullptr, 0,
      nullptr, nullptr, nullptr, 0, bias, 64);

  if (big) {
    // pass 2: h_cov[n] = W @ T[n] + c[n]*kB + b_cov
    gemm_bt<2, short><<<dim3(8, 8, 64), 256, 0, stream>>>(
        weight, 0, Tws, (size_t)1 << 20, h_cov, (size_t)1 << 20, nullptr, 0,
        kB, b_cov, cvec, 0, nullptr, 1024);
  } else {
    // In-place fallback: writing hcov[n] clobbers T^T[m] only for m in {2n-64, 2n-63}.
    // Increasing windows with 2*n1-63 < n0 are race-free; n=63 needs a ws copy.
    short* T63 = (short*)((char*)d_ws + 4096);
    hipMemcpyAsync(T63, Tws + (size_t)63 * (1 << 20), (size_t)2 * 1024 * 1024,
                   hipMemcpyDeviceToDevice, stream);
    const int st[6] = {0, 32, 48, 56, 60, 62};
    const int ln[6] = {32, 16, 8, 4, 2, 1};
    for (int w = 0; w < 6; ++w) {
      gemm_bt<2, short><<<dim3(8, 8, ln[w]), 256, 0, stream>>>(
          weight, 0, Tws + (size_t)st[w] * (1 << 20), (size_t)1 << 20,
          h_cov + (size_t)st[w] * (1 << 20), (size_t)1 << 20, nullptr, 0,
          kB, b_cov, cvec, st[w], nullptr, 1024);
    }
    gemm_bt<2, short><<<dim3(8, 8, 1), 256, 0, stream>>>(
        weight, 0, T63, 0, h_cov + (size_t)63 * (1 << 20), 0, nullptr, 0,
        kB, b_cov, cvec, 63, nullptr, 1024);
  }
}

// Round 2
// 963.356 us; speedup vs baseline: 1.8041x; 1.8041x over previous
//
#include <hip/hip_runtime.h>
#include <hip/hip_bf16.h>

typedef short bf16x8 __attribute__((ext_vector_type(8)));
typedef float f32x4  __attribute__((ext_vector_type(4)));

#define KD 1024

__device__ __forceinline__ short f2bf(float f) {
  unsigned u = __builtin_bit_cast(unsigned, f);
  u += 0x7fffu + ((u >> 16) & 1u);   // round-to-nearest-even
  return (short)(u >> 16);
}

// async global->LDS, 16B per lane; LDS dest = wave-uniform base + lane*16 (m104/m108)
__device__ __forceinline__ void gll16(const short* g, short* l) {
  __builtin_amdgcn_global_load_lds((const __attribute__((address_space(1))) unsigned int*)g,
                                   (__attribute__((address_space(3))) unsigned int*)l,
                                   16, 0, 0);
}

// C[M,N] = A[M,K] @ B[N,K]^T, bf16 inputs, K = N = 1024.
// MODE 0: out = C + bias[col]                  (fp32, rows guarded by M)
// MODE 1: tout[col*1024+row] = bf16(C)         (transposed bf16 store)
// MODE 2: out = C + cvec[ncv0+z]*kB + bcv      (fp32)
template <int MODE>
__global__ __launch_bounds__(256) void gemm_bt(
    const short* __restrict__ A, size_t a_bs,
    const short* __restrict__ B, size_t b_bs,
    float* __restrict__ out, size_t o_bs,
    short* __restrict__ tout, size_t t_bs,
    const float* __restrict__ kB, const float* __restrict__ bcv,
    const float* __restrict__ cvec, int ncv0,
    const float* __restrict__ bias, int M) {
  __shared__ short sA[128 * 32];
  __shared__ short sB[128 * 32];
  const int t = threadIdx.x;
  const int z = blockIdx.z;
  const short* Ab = A + (size_t)z * a_bs;
  const short* Bb = B + (size_t)z * b_bs;
  const int m0 = blockIdx.x * 0 + blockIdx.y * 128, n0 = blockIdx.x * 128;
  const int lane = t & 63, wv = t >> 6;
  const int wm = (wv >> 1) * 64, wn = (wv & 1) * 64;
  const int r16 = lane & 15, q = lane >> 4;

  // staging: wave wv covers 16 rows (1024B) per round; lane i -> row wv*16+i/4, k-chunk (i&3)*8
  const int srow = wv * 16 + (lane >> 2);
  const int skof = (lane & 3) * 8;
  short* lA0 = &sA[(wv * 16) * 32];
  short* lA1 = &sA[(64 + wv * 16) * 32];
  short* lB0 = &sB[(wv * 16) * 32];
  short* lB1 = &sB[(64 + wv * 16) * 32];
  const int ar0 = min(m0 + srow, M - 1);        // clamp for M<128 (h_mean); no-op else
  const int ar1 = min(m0 + 64 + srow, M - 1);
  const short* gA0 = Ab + (size_t)ar0 * KD + skof;
  const short* gA1 = Ab + (size_t)ar1 * KD + skof;
  const short* gB0 = Bb + (size_t)(n0 + srow) * KD + skof;
  const short* gB1 = Bb + (size_t)(n0 + 64 + srow) * KD + skof;

  f32x4 acc[4][4];
  const f32x4 zero4 = {0.f, 0.f, 0.f, 0.f};
#pragma unroll
  for (int i = 0; i < 4; ++i)
#pragma unroll
    for (int j = 0; j < 4; ++j) acc[i][j] = zero4;

  for (int k0 = 0; k0 < KD; k0 += 32) {
    __syncthreads();
    gll16(gA0 + k0, lA0);
    gll16(gA1 + k0, lA1);
    gll16(gB0 + k0, lB0);
    gll16(gB1 + k0, lB1);
    __syncthreads();

    bf16x8 af[4], bf[4];
#pragma unroll
    for (int i = 0; i < 4; ++i) {
      af[i] = *(const bf16x8*)&sA[(wm + i * 16 + r16) * 32 + q * 8];
      bf[i] = *(const bf16x8*)&sB[(wn + i * 16 + r16) * 32 + q * 8];
    }
#pragma unroll
    for (int mi = 0; mi < 4; ++mi)
#pragma unroll
      for (int ni = 0; ni < 4; ++ni)
        acc[mi][ni] = __builtin_amdgcn_mfma_f32_16x16x32_bf16(af[mi], bf[ni], acc[mi][ni], 0, 0, 0);
  }

  float cv = 0.f;
  if (MODE == 2) cv = cvec[ncv0 + z];
  float* ob = out ? out + (size_t)z * o_bs : nullptr;

#pragma unroll
  for (int mi = 0; mi < 4; ++mi) {
#pragma unroll
    for (int ni = 0; ni < 4; ++ni) {
      const int row0 = m0 + wm + mi * 16 + q * 4;
      const int col = n0 + wn + ni * 16 + r16;
      f32x4 a = acc[mi][ni];
      if (MODE == 0) {
        float bv = bias[col];
#pragma unroll
        for (int r = 0; r < 4; ++r)
          if (row0 + r < M) ob[(size_t)(row0 + r) * 1024 + col] = a[r] + bv;
      } else if (MODE == 1) {
        short4 s;
        s.x = f2bf(a[0]); s.y = f2bf(a[1]); s.z = f2bf(a[2]); s.w = f2bf(a[3]);
        *(short4*)(tout + (size_t)z * t_bs + (size_t)col * 1024 + row0) = s;
      } else {
#pragma unroll
        for (int r = 0; r < 4; ++r) {
          size_t idx = (size_t)(row0 + r) * 1024 + col;
          ob[idx] = a[r] + cv * kB[idx] + bcv[idx];
        }
      }
    }
  }
}

// Fused: abf = bf16(a_cov);  c[n] += sum_ij a_cov[n,i,j]*kA[i,j] + a_mean[n]^T kA a_mean[n]
__global__ __launch_bounds__(256) void conv_acov(const float* __restrict__ a_cov,
                                                 const float* __restrict__ a_mean,
                                                 const float* __restrict__ kA,
                                                 short* __restrict__ abf,
                                                 float* __restrict__ c) {
  const int n = blockIdx.x, ch = blockIdx.y, t = threadIdx.x;
  __shared__ float sm[1024];
  for (int j = t; j < 1024; j += 256) sm[j] = a_mean[n * 1024 + j];
  __syncthreads();
  const float4 amv = ((const float4*)sm)[t];
  const size_t cb = ((size_t)n << 20);
  float acc = 0.f;
  for (int i = ch * 64; i < ch * 64 + 64; ++i) {
    float4 Av = ((const float4*)(kA + ((size_t)i << 10)))[t];
    float4 Cv = ((const float4*)(a_cov + cb + ((size_t)i << 10)))[t];
    short4 s;
    s.x = f2bf(Cv.x); s.y = f2bf(Cv.y); s.z = f2bf(Cv.z); s.w = f2bf(Cv.w);
    *(short4*)(abf + cb + ((size_t)i << 10) + t * 4) = s;
    acc += Av.x * Cv.x + Av.y * Cv.y + Av.z * Cv.z + Av.w * Cv.w;
    acc += sm[i] * (Av.x * amv.x + Av.y * amv.y + Av.z * amv.z + Av.w * amv.w);
  }
#pragma unroll
  for (int off = 32; off > 0; off >>= 1) acc += __shfl_down(acc, off);
  __shared__ float red[4];
  if ((t & 63) == 0) red[t >> 6] = acc;
  __syncthreads();
  if (t == 0) atomicAdd(&c[n], red[0] + red[1] + red[2] + red[3]);
}

// generic f32 -> bf16, float4 granularity; n4 = n/4
__global__ __launch_bounds__(256) void convf(const float* __restrict__ src,
                                             short* __restrict__ dst, int n4) {
  int i = blockIdx.x * 256 + threadIdx.x;
  if (i < n4) {
    float4 v = ((const float4*)src)[i];
    short4 s;
    s.x = f2bf(v.x); s.y = f2bf(v.y); s.z = f2bf(v.z); s.w = f2bf(v.w);
    ((short4*)dst)[i] = s;
  }
}

extern "C" void kernel_launch(void* const* d_in, const int* in_sizes, int n_in,
                              void* d_out, int out_size, void* d_ws, size_t ws_size,
                              hipStream_t stream) {
  const float* a_mean = (const float*)d_in[0];
  const float* a_cov  = (const float*)d_in[1];
  const float* weight = (const float*)d_in[2];
  const float* bias   = (const float*)d_in[3];
  const float* kA     = (const float*)d_in[4];
  const float* kB     = (const float*)d_in[5];
  const float* b_cov  = (const float*)d_in[6];
  float* h_mean = (float*)d_out;
  float* h_cov  = h_mean + (size_t)64 * 1024;

  const size_t SLICE = (size_t)1 << 20;          // elems per batch slice (1024*1024)
  float* cvec = (float*)d_ws;
  short* Wbf  = (short*)((char*)d_ws + 4096);    // 2 MB
  short* ambf = Wbf + SLICE;                     // 128 KB
  char*  p    = (char*)(ambf + 65536);
  const size_t need_big = (size_t)((char*)p - (char*)d_ws) + 4 * SLICE * 64; // abf + Tt
  const bool big = ws_size >= need_big;

  short* abf, *Tt;
  if (big) {
    abf = (short*)p;
    Tt  = abf + 64 * SLICE;
  } else {
    abf = (short*)h_cov;                         // lower 128 MB of h_cov region
    Tt  = (short*)(h_cov + 64 * SLICE / 2);      // upper 128 MB
  }

  hipMemsetAsync(cvec, 0, 64 * sizeof(float), stream);
  convf<<<dim3(1024), 256, 0, stream>>>(weight, Wbf, 262144);
  convf<<<dim3(64), 256, 0, stream>>>(a_mean, ambf, 16384);
  conv_acov<<<dim3(64, 16), 256, 0, stream>>>(a_cov, a_mean, kA, abf, cvec);

  // pass 1: Tt[n][l,i] = bf16( (a_cov[n] @ W^T)[i,l] )
  gemm_bt<1><<<dim3(8, 8, 64), 256, 0, stream>>>(
      abf, SLICE, Wbf, 0, nullptr, 0, Tt, SLICE,
      nullptr, nullptr, nullptr, 0, nullptr, 1024);

  // h_mean = a_mean @ W^T + bias (M=64, clamped rows + guarded store)
  gemm_bt<0><<<dim3(8, 1, 1), 256, 0, stream>>>(
      ambf, 0, Wbf, 0, h_mean, 0, nullptr, 0,
      nullptr, nullptr, nullptr, 0, bias, 64);

  if (big) {
    // pass 2: h_cov[n] = W @ T[n] + c[n]*kB + b_cov
    gemm_bt<2><<<dim3(8, 8, 64), 256, 0, stream>>>(
        Wbf, 0, Tt, SLICE, h_cov, SLICE, nullptr, 0,
        kB, b_cov, cvec, 0, nullptr, 1024);
  } else {
    // In-place: h_cov[n] write clobbers Tt[m], m in {2n-64, 2n-63}.
    // Increasing windows keep clobbered m strictly below the window start.
    short* T63 = ambf + 65536;                   // 2 MB scratch in ws
    hipMemcpyAsync(T63, Tt + 63 * SLICE, SLICE * 2, hipMemcpyDeviceToDevice, stream);
    const int st[6] = {0, 32, 48, 56, 60, 62};
    const int ln[6] = {32, 16, 8, 4, 2, 1};
    for (int w = 0; w < 6; ++w) {
      gemm_bt<2><<<dim3(8, 8, ln[w]), 256, 0, stream>>>(
          Wbf, 0, Tt + (size_t)st[w] * SLICE, SLICE,
          h_cov + (size_t)st[w] * SLICE, SLICE, nullptr, 0,
          kB, b_cov, cvec, st[w], nullptr, 1024);
    }
    gemm_bt<2><<<dim3(8, 8, 1), 256, 0, stream>>>(
        Wbf, 0, T63, 0, h_cov + (size_t)63 * SLICE, 0, nullptr, 0,
        kB, b_cov, cvec, 63, nullptr, 1024);
  }
}